// Round 5
// baseline (249.521 us; speedup 1.0000x reference)
//
#include <hip/hip_runtime.h>
#include <math.h>

typedef __bf16 bf16_t;
typedef __bf16 bf16x8 __attribute__((ext_vector_type(8)));
typedef float f32x4 __attribute__((ext_vector_type(4)));
typedef float f32x16 __attribute__((ext_vector_type(16)));

#define GLOAD_LDS16(g, l)                                                      \
  __builtin_amdgcn_global_load_lds(                                            \
      (const __attribute__((address_space(1))) void*)(g),                      \
      (__attribute__((address_space(3))) void*)(l), 16, 0, 0)

// ---------------------------------------------------------------------------
// Prep: build bf16 operands.
//  Acat  [1600][1024] = [enc | ot] rows (b*T+t)
//  Dec   [400][512]
//  WcatT [640][1024]  = concat(W_enc;W_ot)^T   (row f, col k)
//  WdecT [640][512]   = W_dec^T
//  WoutT [1024][640]  = W_out^T                 (row v, col f)
// ---------------------------------------------------------------------------
__global__ __launch_bounds__(256) void prep_kernel(
    const float* __restrict__ enc, const float* __restrict__ dec,
    const float* __restrict__ ot, const float* __restrict__ W_enc,
    const float* __restrict__ W_ot, const float* __restrict__ W_dec,
    const float* __restrict__ W_out, bf16_t* __restrict__ Acat,
    bf16_t* __restrict__ Dec, bf16_t* __restrict__ WcatT,
    bf16_t* __restrict__ WdecT, bf16_t* __restrict__ WoutT) {
  int idx = blockIdx.x * 256 + threadIdx.x;
  const int N0 = 1600 * 1024, N1 = 400 * 512, N2 = 640 * 1024, N3 = 640 * 512,
            N4 = 1024 * 640;
  if (idx < N0) {
    int r = idx >> 10, c = idx & 1023;
    float v = (c < 512) ? enc[(r << 9) + c] : ot[(r << 9) + (c - 512)];
    Acat[idx] = (bf16_t)v;
    return;
  }
  idx -= N0;
  if (idx < N1) {
    Dec[idx] = (bf16_t)dec[idx];
    return;
  }
  idx -= N1;
  if (idx < N2) {
    int f = idx >> 10, k = idx & 1023;
    float v = (k < 512) ? W_enc[k * 640 + f] : W_ot[(k - 512) * 640 + f];
    WcatT[idx] = (bf16_t)v;
    return;
  }
  idx -= N2;
  if (idx < N3) {
    int f = idx >> 9, k = idx & 511;
    WdecT[idx] = (bf16_t)W_dec[k * 640 + f];
    return;
  }
  idx -= N3;
  if (idx < N4) {
    int v = idx / 640, f = idx - v * 640;
    WoutT[idx] = (bf16_t)W_out[f * 1024 + v];
    return;
  }
}

// ---------------------------------------------------------------------------
// Stage 1: out[M][640] = tanh(A[M][K] @ Bt[640][K]^T + bias1 (+ bias2))
// ---------------------------------------------------------------------------
__global__ __launch_bounds__(256) void gemm_tanh_kernel(
    const bf16_t* __restrict__ A, const bf16_t* __restrict__ Bt,
    const float* __restrict__ bias1, const float* __restrict__ bias2,
    float* __restrict__ out, int M, int K) {
  __shared__ bf16_t As[64 * 32];
  __shared__ bf16_t Bs[64 * 32];
  const int tid = threadIdx.x;
  const int wid = tid >> 6, lane = tid & 63;
  const int wm = wid >> 1, wn = wid & 1;
  const int r0 = blockIdx.y * 64, n0 = blockIdx.x * 64;

  const int ia = wid * 16 + (lane >> 2);
  const int sa = lane & 3;
  int ra = r0 + ia;
  if (ra > M - 1) ra = M - 1;
  const bf16_t* gA = A + (size_t)ra * K + sa * 8;
  const bf16_t* gB = Bt + (size_t)(n0 + ia) * K + sa * 8;
  bf16_t* lA = As + wid * 512;
  bf16_t* lB = Bs + wid * 512;

  f32x4 acc[2][2] = {};
  const int lr = lane & 15, kg = lane >> 4;
  const int steps = K >> 5;
  for (int ks = 0; ks < steps; ++ks) {
    GLOAD_LDS16(gA + ks * 32, lA);
    GLOAD_LDS16(gB + ks * 32, lB);
    __syncthreads();
    bf16x8 af[2], bfr[2];
#pragma unroll
    for (int a = 0; a < 2; ++a)
      af[a] = *(const bf16x8*)(As + (wm * 32 + a * 16 + lr) * 32 + kg * 8);
#pragma unroll
    for (int b = 0; b < 2; ++b)
      bfr[b] = *(const bf16x8*)(Bs + (wn * 32 + b * 16 + lr) * 32 + kg * 8);
#pragma unroll
    for (int a = 0; a < 2; ++a)
#pragma unroll
      for (int b = 0; b < 2; ++b)
        acc[a][b] =
            __builtin_amdgcn_mfma_f32_16x16x32_bf16(af[a], bfr[b], acc[a][b], 0, 0, 0);
    __syncthreads();
  }
#pragma unroll
  for (int a = 0; a < 2; ++a)
#pragma unroll
    for (int b = 0; b < 2; ++b) {
      int col = n0 + wn * 32 + b * 16 + lr;
      float bv = bias1[col] + (bias2 ? bias2[col] : 0.0f);
#pragma unroll
      for (int j = 0; j < 4; ++j) {
        int rg = r0 + wm * 32 + a * 16 + kg * 4 + j;
        if (rg < M) out[(size_t)rg * 640 + col] = tanhf(acc[a][b][j] + bv);
      }
    }
}

// ---------------------------------------------------------------------------
// Materialize joint A: Amat[80128][640] bf16 = tanh(fused+proj_dec) via the
// tanh addition identity on precomputed tanh tables. Pad rows [80000,80128)
// are zeroed. One thread per 8 elements; memory-bound (~102.6 MB write).
// ---------------------------------------------------------------------------
__global__ __launch_bounds__(256) void materialize_joint_kernel(
    const float* __restrict__ ta,   // [1600][640]
    const float* __restrict__ tb,   // [400][640]
    bf16_t* __restrict__ Amat) {    // [80128][640]
  const int idx = blockIdx.x * 256 + threadIdx.x;  // 0 .. 80128*80-1
  const int row = idx / 80;
  const int s = idx - row * 80;
  bf16x8 jv;
  if (row >= 80000) {
#pragma unroll
    for (int e = 0; e < 8; ++e) jv[e] = (bf16_t)0.0f;
    *(bf16x8*)(Amat + (size_t)row * 640 + s * 8) = jv;
    return;
  }
  const int frow = row / 50;          // b*T + t
  const int bidx = row / 10000;       // b
  const int u = row - frow * 50;      // u
  const float* taP = ta + (size_t)frow * 640 + s * 8;
  const float* tbP = tb + (size_t)(bidx * 50 + u) * 640 + s * 8;
#pragma unroll
  for (int h = 0; h < 2; ++h) {
    f32x4 xa = *(const f32x4*)(taP + h * 4);
    f32x4 xb = *(const f32x4*)(tbP + h * 4);
#pragma unroll
    for (int e = 0; e < 4; ++e) {
      float d = fmaxf(1.0f + xa[e] * xb[e], 1e-6f);
      jv[h * 4 + e] = (bf16_t)((xa[e] + xb[e]) * __builtin_amdgcn_rcpf(d));
    }
  }
  *(bf16x8*)(Amat + (size_t)row * 640 + s * 8) = jv;
}

// ---------------------------------------------------------------------------
// Stage 2: phase-scheduled GEMM (T3+T4+T2+T5 port of the 8-phase template).
//  out[80000][1024] = Amat[80128][640] @ WoutT[1024][640]^T + b_out
//  Tile 256x256, 512 thr, 8 waves 2(M)x4(N), wave tile 128x64 of 32x32x16
//  MFMA. BK=32 -> 20 K-tiles, 2 phases each (k-slice 16).
//  LDS: 4-buffer ring, 32 KB/buffer (A 16K + B 16K) = 128 KiB.
//  Prefetch distance 2 K-tiles; counted vmcnt(6) in steady state (T4).
//  T2 swizzle: 16B-slot ^= (row&3), applied on gload source AND ds_read
//  (both-sides rule); frag reads hit the 8-cy bank floor.
//  One raw s_barrier per K-tile (ring distance makes mid-phases race-free).
// ---------------------------------------------------------------------------
__global__ __launch_bounds__(512, 1) void joint_gemm8_kernel(
    const bf16_t* __restrict__ Amat,   // [80128][640]
    const bf16_t* __restrict__ WoutT,  // [1024][640]
    const float* __restrict__ b_out,   // [1024]
    float* __restrict__ out) {         // [80000][1024]
  __shared__ bf16_t lds[4][16384];  // per buf: A [0,8192), B [8192,16384)
  const int tid = threadIdx.x;
  const int wid = tid >> 6, l = tid & 63;
  const int wm = wid >> 2, wn = wid & 3;

  // XCD-grouped mapping: bid%8 selects XCD (round-robin heuristic); the 4
  // N-siblings of one M-panel land on the same XCD -> A panel L2-reuse.
  const int bid = blockIdx.x;  // 0..1279
  const int mb = (bid & 7) + ((bid >> 5) << 3);
  const int nb = (bid >> 3) & 3;
  if (mb >= 313) return;  // pad blocks
  const int r0 = mb * 256, n0 = nb * 256;

  // ---- staging: per-lane pre-swizzled global sources (rule 21) ----
  // chunk = 16 rows x 64B; lane l -> row crow=l>>2, 16B-slot q=l&3.
  // LDS slot q holds data of col-slot q ^ (row&3).
  const int crow = l >> 2;
  const int cxor = (((l & 3) ^ (crow & 3)) << 3);  // element offset
  const bf16_t* srcA0 = Amat + (size_t)(r0 + wid * 16 + crow) * 640 + cxor;
  const bf16_t* srcA1 = srcA0 + (size_t)128 * 640;
  const bf16_t* srcB0 = WoutT + (size_t)(n0 + wid * 16 + crow) * 640 + cxor;
  const bf16_t* srcB1 = srcB0 + (size_t)128 * 640;
  // wave-uniform LDS dest elem offsets (HW adds lane*16B)
  const int dA0 = wid * 512, dA1 = dA0 + 4096;
  const int dB0 = 8192 + wid * 512, dB1 = dB0 + 4096;

  // ---- frag read indices (32x32x16: row = l&31, kg = l>>5) ----
  int rowA[4], rowB[2];
#pragma unroll
  for (int mf = 0; mf < 4; ++mf) rowA[mf] = wm * 128 + mf * 32 + (l & 31);
#pragma unroll
  for (int nf = 0; nf < 2; ++nf) rowB[nf] = wn * 64 + nf * 32 + (l & 31);
  const int kg = l >> 5;

  f32x16 acc[4][2] = {};

  // ---- prologue: stage kt=0 (buf0) and kt=1 (buf1) ----
  GLOAD_LDS16(srcA0, &lds[0][dA0]);
  GLOAD_LDS16(srcA1, &lds[0][dA1]);
  GLOAD_LDS16(srcB0, &lds[0][dB0]);
  GLOAD_LDS16(srcB1, &lds[0][dB1]);
  GLOAD_LDS16(srcA0 + 32, &lds[1][dA0]);
  GLOAD_LDS16(srcA1 + 32, &lds[1][dA1]);
  GLOAD_LDS16(srcB0 + 32, &lds[1][dB0]);
  GLOAD_LDS16(srcB1 + 32, &lds[1][dB1]);

#pragma unroll 1
  for (int kt = 0; kt < 20; ++kt) {
    const int buf = kt & 3;
    const int pbuf = (kt + 2) & 3;
    const bf16_t* Ab = &lds[buf][0];
    const bf16_t* Bb = &lds[buf][8192];

    // ---- phase 0: prefetch A(kt+2) | wait kt landed (counted) | MFMA ks=0
    if (kt < 18) {
      const size_t ko = (size_t)(kt + 2) * 32;
      GLOAD_LDS16(srcA0 + ko, &lds[pbuf][dA0]);
      GLOAD_LDS16(srcA1 + ko, &lds[pbuf][dA1]);
      asm volatile("s_waitcnt vmcnt(6)" ::: "memory");
    } else if (kt == 18) {
      asm volatile("s_waitcnt vmcnt(4)" ::: "memory");
    } else {
      asm volatile("s_waitcnt vmcnt(0)" ::: "memory");
    }
    __builtin_amdgcn_sched_barrier(0);
    __builtin_amdgcn_s_barrier();
    __builtin_amdgcn_sched_barrier(0);
    {
      bf16x8 af[4], bfr[2];
#pragma unroll
      for (int mf = 0; mf < 4; ++mf) {
        const int slot = kg ^ (rowA[mf] & 3);  // ks=0: slot_data = kg
        af[mf] = *(const bf16x8*)(Ab + rowA[mf] * 32 + slot * 8);
      }
#pragma unroll
      for (int nf = 0; nf < 2; ++nf) {
        const int slot = kg ^ (rowB[nf] & 3);
        bfr[nf] = *(const bf16x8*)(Bb + rowB[nf] * 32 + slot * 8);
      }
      __builtin_amdgcn_s_setprio(1);
#pragma unroll
      for (int mf = 0; mf < 4; ++mf)
#pragma unroll
        for (int nf = 0; nf < 2; ++nf)
          acc[mf][nf] = __builtin_amdgcn_mfma_f32_32x32x16_bf16(
              af[mf], bfr[nf], acc[mf][nf], 0, 0, 0);
      __builtin_amdgcn_s_setprio(0);
    }

    // ---- phase 1: prefetch B(kt+2) | MFMA ks=1 ----
    if (kt < 18) {
      const size_t ko = (size_t)(kt + 2) * 32;
      GLOAD_LDS16(srcB0 + ko, &lds[pbuf][dB0]);
      GLOAD_LDS16(srcB1 + ko, &lds[pbuf][dB1]);
    }
    {
      bf16x8 af[4], bfr[2];
#pragma unroll
      for (int mf = 0; mf < 4; ++mf) {
        const int slot = (2 + kg) ^ (rowA[mf] & 3);  // ks=1: slot_data = 2+kg
        af[mf] = *(const bf16x8*)(Ab + rowA[mf] * 32 + slot * 8);
      }
#pragma unroll
      for (int nf = 0; nf < 2; ++nf) {
        const int slot = (2 + kg) ^ (rowB[nf] & 3);
        bfr[nf] = *(const bf16x8*)(Bb + rowB[nf] * 32 + slot * 8);
      }
      __builtin_amdgcn_s_setprio(1);
#pragma unroll
      for (int mf = 0; mf < 4; ++mf)
#pragma unroll
        for (int nf = 0; nf < 2; ++nf)
          acc[mf][nf] = __builtin_amdgcn_mfma_f32_32x32x16_bf16(
              af[mf], bfr[nf], acc[mf][nf], 0, 0, 0);
      __builtin_amdgcn_s_setprio(0);
    }
  }

  // ---- epilogue: + b_out, store f32 (C/D: col=l&31, row=(reg&3)+8*(reg>>2)+4*(l>>5)) ----
#pragma unroll
  for (int nf = 0; nf < 2; ++nf) {
    const int col = n0 + rowB[nf];
    const float bv = b_out[col];
#pragma unroll
    for (int mf = 0; mf < 4; ++mf) {
      const int base = r0 + wm * 128 + mf * 32 + 4 * kg;
      const f32x16 v = acc[mf][nf];
#pragma unroll
      for (int reg = 0; reg < 16; ++reg) {
        const int row = base + (reg & 3) + 8 * (reg >> 2);
        if (row < 80000) out[(size_t)row * 1024 + col] = v[reg] + bv;
      }
    }
  }
}

// ---------------------------------------------------------------------------
extern "C" void kernel_launch(void* const* d_in, const int* in_sizes, int n_in,
                              void* d_out, int out_size, void* d_ws,
                              size_t ws_size, hipStream_t stream) {
  const float* enc = (const float*)d_in[0];
  const float* dec = (const float*)d_in[1];
  const float* ot = (const float*)d_in[2];
  const float* W_enc = (const float*)d_in[3];
  const float* b_enc = (const float*)d_in[4];
  const float* W_ot = (const float*)d_in[5];
  const float* b_ot = (const float*)d_in[6];
  const float* W_dec = (const float*)d_in[7];
  const float* b_dec = (const float*)d_in[8];
  const float* W_out = (const float*)d_in[9];
  const float* b_out = (const float*)d_in[10];
  float* out = (float*)d_out;

  char* ws = (char*)d_ws;
  size_t off = 0;
  auto alloc = [&](size_t bytes) {
    void* p = ws + off;
    off += (bytes + 255) & ~(size_t)255;
    return p;
  };
  float* ta = (float*)alloc(1600 * 640 * 4);        // tanh(fused)
  float* tb = (float*)alloc(400 * 640 * 4);         // tanh(proj_dec)
  bf16_t* Acat = (bf16_t*)alloc(1600 * 1024 * 2);
  bf16_t* Dec = (bf16_t*)alloc(400 * 512 * 2);
  bf16_t* WcatT = (bf16_t*)alloc(640 * 1024 * 2);
  bf16_t* WdecT = (bf16_t*)alloc(640 * 512 * 2);
  bf16_t* WoutT = (bf16_t*)alloc(1024 * 640 * 2);
  bf16_t* Amat = (bf16_t*)alloc((size_t)80128 * 640 * 2);  // joint bf16

  prep_kernel<<<13600, 256, 0, stream>>>(enc, dec, ot, W_enc, W_ot, W_dec,
                                         W_out, Acat, Dec, WcatT, WdecT, WoutT);
  gemm_tanh_kernel<<<dim3(10, 25), 256, 0, stream>>>(Acat, WcatT, b_enc, b_ot,
                                                     ta, 1600, 1024);
  gemm_tanh_kernel<<<dim3(10, 7), 256, 0, stream>>>(Dec, WdecT, b_dec, nullptr,
                                                    tb, 400, 512);
  materialize_joint_kernel<<<25040, 256, 0, stream>>>(ta, tb, Amat);
  joint_gemm8_kernel<<<1280, 512, 0, stream>>>(Amat, WoutT, b_out, out);
}

// Round 6
// 232.864 us; speedup vs baseline: 1.0715x; 1.0715x over previous
//
#include <hip/hip_runtime.h>
#include <math.h>

typedef __bf16 bf16_t;
typedef __bf16 bf16x8 __attribute__((ext_vector_type(8)));
typedef float f32x4 __attribute__((ext_vector_type(4)));
typedef float f32x16 __attribute__((ext_vector_type(16)));

#define GLOAD_LDS16(g, l)                                                      \
  __builtin_amdgcn_global_load_lds(                                            \
      (const __attribute__((address_space(1))) void*)(g),                      \
      (__attribute__((address_space(3))) void*)(l), 16, 0, 0)

// ---------------------------------------------------------------------------
// Prep: build bf16 operands.
//  Acat  [1600][1024] = [enc | ot] rows (b*T+t)
//  Dec   [400][512]
//  WcatT [640][1024]  = concat(W_enc;W_ot)^T   (row f, col k)
//  WdecT [640][512]   = W_dec^T
//  WoutT [1024][640]  = W_out^T                 (row v, col f)
// ---------------------------------------------------------------------------
__global__ __launch_bounds__(256) void prep_kernel(
    const float* __restrict__ enc, const float* __restrict__ dec,
    const float* __restrict__ ot, const float* __restrict__ W_enc,
    const float* __restrict__ W_ot, const float* __restrict__ W_dec,
    const float* __restrict__ W_out, bf16_t* __restrict__ Acat,
    bf16_t* __restrict__ Dec, bf16_t* __restrict__ WcatT,
    bf16_t* __restrict__ WdecT, bf16_t* __restrict__ WoutT) {
  int idx = blockIdx.x * 256 + threadIdx.x;
  const int N0 = 1600 * 1024, N1 = 400 * 512, N2 = 640 * 1024, N3 = 640 * 512,
            N4 = 1024 * 640;
  if (idx < N0) {
    int r = idx >> 10, c = idx & 1023;
    float v = (c < 512) ? enc[(r << 9) + c] : ot[(r << 9) + (c - 512)];
    Acat[idx] = (bf16_t)v;
    return;
  }
  idx -= N0;
  if (idx < N1) {
    Dec[idx] = (bf16_t)dec[idx];
    return;
  }
  idx -= N1;
  if (idx < N2) {
    int f = idx >> 10, k = idx & 1023;
    float v = (k < 512) ? W_enc[k * 640 + f] : W_ot[(k - 512) * 640 + f];
    WcatT[idx] = (bf16_t)v;
    return;
  }
  idx -= N2;
  if (idx < N3) {
    int f = idx >> 9, k = idx & 511;
    WdecT[idx] = (bf16_t)W_dec[k * 640 + f];
    return;
  }
  idx -= N3;
  if (idx < N4) {
    int v = idx / 640, f = idx - v * 640;
    WoutT[idx] = (bf16_t)W_out[f * 1024 + v];
    return;
  }
}

// ---------------------------------------------------------------------------
// Stage 1: out[M][640] = tanh(A[M][K] @ Bt[640][K]^T + bias1 (+ bias2))
// ---------------------------------------------------------------------------
__global__ __launch_bounds__(256) void gemm_tanh_kernel(
    const bf16_t* __restrict__ A, const bf16_t* __restrict__ Bt,
    const float* __restrict__ bias1, const float* __restrict__ bias2,
    float* __restrict__ out, int M, int K) {
  __shared__ bf16_t As[64 * 32];
  __shared__ bf16_t Bs[64 * 32];
  const int tid = threadIdx.x;
  const int wid = tid >> 6, lane = tid & 63;
  const int wm = wid >> 1, wn = wid & 1;
  const int r0 = blockIdx.y * 64, n0 = blockIdx.x * 64;

  const int ia = wid * 16 + (lane >> 2);
  const int sa = lane & 3;
  int ra = r0 + ia;
  if (ra > M - 1) ra = M - 1;
  const bf16_t* gA = A + (size_t)ra * K + sa * 8;
  const bf16_t* gB = Bt + (size_t)(n0 + ia) * K + sa * 8;
  bf16_t* lA = As + wid * 512;
  bf16_t* lB = Bs + wid * 512;

  f32x4 acc[2][2] = {};
  const int lr = lane & 15, kg = lane >> 4;
  const int steps = K >> 5;
  for (int ks = 0; ks < steps; ++ks) {
    GLOAD_LDS16(gA + ks * 32, lA);
    GLOAD_LDS16(gB + ks * 32, lB);
    __syncthreads();
    bf16x8 af[2], bfr[2];
#pragma unroll
    for (int a = 0; a < 2; ++a)
      af[a] = *(const bf16x8*)(As + (wm * 32 + a * 16 + lr) * 32 + kg * 8);
#pragma unroll
    for (int b = 0; b < 2; ++b)
      bfr[b] = *(const bf16x8*)(Bs + (wn * 32 + b * 16 + lr) * 32 + kg * 8);
#pragma unroll
    for (int a = 0; a < 2; ++a)
#pragma unroll
      for (int b = 0; b < 2; ++b)
        acc[a][b] =
            __builtin_amdgcn_mfma_f32_16x16x32_bf16(af[a], bfr[b], acc[a][b], 0, 0, 0);
    __syncthreads();
  }
#pragma unroll
  for (int a = 0; a < 2; ++a)
#pragma unroll
    for (int b = 0; b < 2; ++b) {
      int col = n0 + wn * 32 + b * 16 + lr;
      float bv = bias1[col] + (bias2 ? bias2[col] : 0.0f);
#pragma unroll
      for (int j = 0; j < 4; ++j) {
        int rg = r0 + wm * 32 + a * 16 + kg * 4 + j;
        if (rg < M) out[(size_t)rg * 640 + col] = tanhf(acc[a][b][j] + bv);
      }
    }
}

// ---------------------------------------------------------------------------
// Materialize joint A: Amat[80128][640] bf16 = tanh(fused+proj_dec) via the
// tanh addition identity on precomputed tanh tables. Pad rows zeroed.
// ---------------------------------------------------------------------------
__global__ __launch_bounds__(256) void materialize_joint_kernel(
    const float* __restrict__ ta,   // [1600][640]
    const float* __restrict__ tb,   // [400][640]
    bf16_t* __restrict__ Amat) {    // [80128][640]
  const int idx = blockIdx.x * 256 + threadIdx.x;  // 0 .. 80128*80-1
  const int row = idx / 80;
  const int s = idx - row * 80;
  bf16x8 jv;
  if (row >= 80000) {
#pragma unroll
    for (int e = 0; e < 8; ++e) jv[e] = (bf16_t)0.0f;
    *(bf16x8*)(Amat + (size_t)row * 640 + s * 8) = jv;
    return;
  }
  const int frow = row / 50;          // b*T + t
  const int bidx = row / 10000;       // b
  const int u = row - frow * 50;      // u
  const float* taP = ta + (size_t)frow * 640 + s * 8;
  const float* tbP = tb + (size_t)(bidx * 50 + u) * 640 + s * 8;
#pragma unroll
  for (int h = 0; h < 2; ++h) {
    f32x4 xa = *(const f32x4*)(taP + h * 4);
    f32x4 xb = *(const f32x4*)(tbP + h * 4);
#pragma unroll
    for (int e = 0; e < 4; ++e) {
      float d = fmaxf(1.0f + xa[e] * xb[e], 1e-6f);
      jv[h * 4 + e] = (bf16_t)((xa[e] + xb[e]) * __builtin_amdgcn_rcpf(d));
    }
  }
  *(bf16x8*)(Amat + (size_t)row * 640 + s * 8) = jv;
}

// ---------------------------------------------------------------------------
// Stage 2: phase-scheduled GEMM.
//  out[80000][1024] = Amat[80128][640] @ WoutT[1024][640]^T + b_out
//  Tile 256x256, 512 thr, 8 waves 2(M)x4(N), wave tile 128x64 of 32x32x16
//  MFMA. BK=32 -> 20 K-tiles, 2 phases each (k-slice 16).
//  LDS: 4-buffer ring, 32 KB/buffer; prefetch distance 2; counted vmcnt(6).
//  SWIZZLE (fixed R6): bank position of a b128 read = (row&1)*16 + slot*4.
//  slot ^= (row>>1)&3 makes (row&1,slot) cover all 8 16B-positions over any
//  8 consecutive rows -> conflict-free frag reads. Write side: gload_lds
//  writes lane l -> row l>>2, slot l&3 linearly, so the per-lane global
//  source column is pre-permuted by ^((l>>3)&3) (both-sides rule).
// ---------------------------------------------------------------------------
__global__ __launch_bounds__(512, 1) void joint_gemm8_kernel(
    const bf16_t* __restrict__ Amat,   // [80128][640]
    const bf16_t* __restrict__ WoutT,  // [1024][640]
    const float* __restrict__ b_out,   // [1024]
    float* __restrict__ out) {         // [80000][1024]
  __shared__ bf16_t lds[4][16384];  // per buf: A [0,8192), B [8192,16384)
  const int tid = threadIdx.x;
  const int wid = tid >> 6, l = tid & 63;
  const int wm = wid >> 2, wn = wid & 3;

  // XCD-grouped mapping: 4 N-siblings of one M-panel on one XCD.
  const int bid = blockIdx.x;  // 0..1279
  const int mb = (bid & 7) + ((bid >> 5) << 3);
  const int nb = (bid >> 3) & 3;
  if (mb >= 313) return;  // pad blocks
  const int r0 = mb * 256, n0 = nb * 256;

  // ---- staging: per-lane pre-swizzled global sources ----
  // chunk = 16 rows x 64B; lane l -> row crow=l>>2, 16B-slot q=l&3.
  // LDS slot q of row r holds data col-slot q ^ ((r>>1)&3) -> source col
  // slot for lane l is (l&3) ^ ((l>>3)&3).
  const int crow = l >> 2;
  const int cxor = (((l & 3) ^ ((l >> 3) & 3)) << 3);  // element offset
  const bf16_t* srcA0 = Amat + (size_t)(r0 + wid * 16 + crow) * 640 + cxor;
  const bf16_t* srcA1 = srcA0 + (size_t)128 * 640;
  const bf16_t* srcB0 = WoutT + (size_t)(n0 + wid * 16 + crow) * 640 + cxor;
  const bf16_t* srcB1 = srcB0 + (size_t)128 * 640;
  // wave-uniform LDS dest elem offsets (HW adds lane*16B)
  const int dA0 = wid * 512, dA1 = dA0 + 4096;
  const int dB0 = 8192 + wid * 512, dB1 = dB0 + 4096;

  // ---- frag read indices (32x32x16: row = l&31, kg = l>>5) ----
  int rowA[4], rowB[2];
#pragma unroll
  for (int mf = 0; mf < 4; ++mf) rowA[mf] = wm * 128 + mf * 32 + (l & 31);
#pragma unroll
  for (int nf = 0; nf < 2; ++nf) rowB[nf] = wn * 64 + nf * 32 + (l & 31);
  const int kg = l >> 5;

  f32x16 acc[4][2] = {};

  // ---- prologue: stage kt=0 (buf0) and kt=1 (buf1) ----
  GLOAD_LDS16(srcA0, &lds[0][dA0]);
  GLOAD_LDS16(srcA1, &lds[0][dA1]);
  GLOAD_LDS16(srcB0, &lds[0][dB0]);
  GLOAD_LDS16(srcB1, &lds[0][dB1]);
  GLOAD_LDS16(srcA0 + 32, &lds[1][dA0]);
  GLOAD_LDS16(srcA1 + 32, &lds[1][dA1]);
  GLOAD_LDS16(srcB0 + 32, &lds[1][dB0]);
  GLOAD_LDS16(srcB1 + 32, &lds[1][dB1]);

#pragma unroll 1
  for (int kt = 0; kt < 20; ++kt) {
    const int buf = kt & 3;
    const int pbuf = (kt + 2) & 3;
    const bf16_t* Ab = &lds[buf][0];
    const bf16_t* Bb = &lds[buf][8192];

    // ---- phase 0: prefetch A(kt+2) | wait kt landed (counted) | MFMA ks=0
    if (kt < 18) {
      const size_t ko = (size_t)(kt + 2) * 32;
      GLOAD_LDS16(srcA0 + ko, &lds[pbuf][dA0]);
      GLOAD_LDS16(srcA1 + ko, &lds[pbuf][dA1]);
      asm volatile("s_waitcnt vmcnt(6)" ::: "memory");
    } else if (kt == 18) {
      asm volatile("s_waitcnt vmcnt(4)" ::: "memory");
    } else {
      asm volatile("s_waitcnt vmcnt(0)" ::: "memory");
    }
    __builtin_amdgcn_sched_barrier(0);
    __builtin_amdgcn_s_barrier();
    __builtin_amdgcn_sched_barrier(0);
    {
      bf16x8 af[4], bfr[2];
#pragma unroll
      for (int mf = 0; mf < 4; ++mf) {
        const int slot = kg ^ ((rowA[mf] >> 1) & 3);  // ks=0: slot_data = kg
        af[mf] = *(const bf16x8*)(Ab + rowA[mf] * 32 + slot * 8);
      }
#pragma unroll
      for (int nf = 0; nf < 2; ++nf) {
        const int slot = kg ^ ((rowB[nf] >> 1) & 3);
        bfr[nf] = *(const bf16x8*)(Bb + rowB[nf] * 32 + slot * 8);
      }
      __builtin_amdgcn_s_setprio(1);
#pragma unroll
      for (int mf = 0; mf < 4; ++mf)
#pragma unroll
        for (int nf = 0; nf < 2; ++nf)
          acc[mf][nf] = __builtin_amdgcn_mfma_f32_32x32x16_bf16(
              af[mf], bfr[nf], acc[mf][nf], 0, 0, 0);
      __builtin_amdgcn_s_setprio(0);
    }

    // ---- phase 1: prefetch B(kt+2) | MFMA ks=1 ----
    if (kt < 18) {
      const size_t ko = (size_t)(kt + 2) * 32;
      GLOAD_LDS16(srcB0 + ko, &lds[pbuf][dB0]);
      GLOAD_LDS16(srcB1 + ko, &lds[pbuf][dB1]);
    }
    {
      bf16x8 af[4], bfr[2];
#pragma unroll
      for (int mf = 0; mf < 4; ++mf) {
        const int slot = (2 + kg) ^ ((rowA[mf] >> 1) & 3);  // ks=1: 2+kg
        af[mf] = *(const bf16x8*)(Ab + rowA[mf] * 32 + slot * 8);
      }
#pragma unroll
      for (int nf = 0; nf < 2; ++nf) {
        const int slot = (2 + kg) ^ ((rowB[nf] >> 1) & 3);
        bfr[nf] = *(const bf16x8*)(Bb + rowB[nf] * 32 + slot * 8);
      }
      __builtin_amdgcn_s_setprio(1);
#pragma unroll
      for (int mf = 0; mf < 4; ++mf)
#pragma unroll
        for (int nf = 0; nf < 2; ++nf)
          acc[mf][nf] = __builtin_amdgcn_mfma_f32_32x32x16_bf16(
              af[mf], bfr[nf], acc[mf][nf], 0, 0, 0);
      __builtin_amdgcn_s_setprio(0);
    }
  }

  // ---- epilogue: + b_out, store f32 (C/D: col=l&31, row=(reg&3)+8*(reg>>2)+4*(l>>5)) ----
#pragma unroll
  for (int nf = 0; nf < 2; ++nf) {
    const int col = n0 + rowB[nf];
    const float bv = b_out[col];
#pragma unroll
    for (int mf = 0; mf < 4; ++mf) {
      const int base = r0 + wm * 128 + mf * 32 + 4 * kg;
      const f32x16 v = acc[mf][nf];
#pragma unroll
      for (int reg = 0; reg < 16; ++reg) {
        const int row = base + (reg & 3) + 8 * (reg >> 2);
        if (row < 80000) out[(size_t)row * 1024 + col] = v[reg] + bv;
      }
    }
  }
}

// ---------------------------------------------------------------------------
extern "C" void kernel_launch(void* const* d_in, const int* in_sizes, int n_in,
                              void* d_out, int out_size, void* d_ws,
                              size_t ws_size, hipStream_t stream) {
  const float* enc = (const float*)d_in[0];
  const float* dec = (const float*)d_in[1];
  const float* ot = (const float*)d_in[2];
  const float* W_enc = (const float*)d_in[3];
  const float* b_enc = (const float*)d_in[4];
  const float* W_ot = (const float*)d_in[5];
  const float* b_ot = (const float*)d_in[6];
  const float* W_dec = (const float*)d_in[7];
  const float* b_dec = (const float*)d_in[8];
  const float* W_out = (const float*)d_in[9];
  const float* b_out = (const float*)d_in[10];
  float* out = (float*)d_out;

  char* ws = (char*)d_ws;
  size_t off = 0;
  auto alloc = [&](size_t bytes) {
    void* p = ws + off;
    off += (bytes + 255) & ~(size_t)255;
    return p;
  };
  float* ta = (float*)alloc(1600 * 640 * 4);        // tanh(fused)
  float* tb = (float*)alloc(400 * 640 * 4);         // tanh(proj_dec)
  bf16_t* Acat = (bf16_t*)alloc(1600 * 1024 * 2);
  bf16_t* Dec = (bf16_t*)alloc(400 * 512 * 2);
  bf16_t* WcatT = (bf16_t*)alloc(640 * 1024 * 2);
  bf16_t* WdecT = (bf16_t*)alloc(640 * 512 * 2);
  bf16_t* WoutT = (bf16_t*)alloc(1024 * 640 * 2);
  bf16_t* Amat = (bf16_t*)alloc((size_t)80128 * 640 * 2);  // joint bf16

  prep_kernel<<<13600, 256, 0, stream>>>(enc, dec, ot, W_enc, W_ot, W_dec,
                                         W_out, Acat, Dec, WcatT, WdecT, WoutT);
  gemm_tanh_kernel<<<dim3(10, 25), 256, 0, stream>>>(Acat, WcatT, b_enc, b_ot,
                                                     ta, 1600, 1024);
  gemm_tanh_kernel<<<dim3(10, 7), 256, 0, stream>>>(Dec, WdecT, b_dec, nullptr,
                                                    tb, 400, 512);
  materialize_joint_kernel<<<25040, 256, 0, stream>>>(ta, tb, Amat);
  joint_gemm8_kernel<<<1280, 512, 0, stream>>>(Amat, WoutT, b_out, out);
}